// Round 2
// baseline (1862.822 us; speedup 1.0000x reference)
//
#include <hip/hip_runtime.h>
#include <hip/hip_bf16.h>

// Problem constants
#define Bn 8
#define CIN 64
#define COUT_ 64
#define Hh 128
#define Ww 128
#define HW 16384

// ws layout (f32 units)
#define W1R_OFF   ((size_t)0)            // 128*25*64 = 204800
#define W2R_OFF   (W1R_OFF + 204800)     // 64*9*64 = 36864
#define WOFFR_OFF (W2R_OFF + 36864)      // 64*9*27 = 15552
#define WDCNR_OFF (WOFFR_OFF + 15552)    // 576*64 = 36864
#define B1_OFF    (WDCNR_OFF + 36864)    // 64
#define B2_OFF    (B1_OFF + 64)          // 64
#define BOFF_OFF  (B2_OFF + 64)          // 32 (27 used)
#define BDCN_OFF  (BOFF_OFF + 32)        // 64
#define FEAT1_OFF (BDCN_OFF + 64)        // 8*64*16384 = 8388608
#define FEAT2_OFF (FEAT1_OFF + 8388608)
#define OO_OFF    (FEAT2_OFF + 8388608)  // 8*27*16384 = 3538944
// total = 20,610,464 f32 = 82.44 MB

// ---------------- weight/bias prep: transpose to [c][tap][co] ----------------
__global__ void prep_kernel(const float* __restrict__ w1, const float* __restrict__ b1,
                            const float* __restrict__ w2, const float* __restrict__ b2,
                            const float* __restrict__ w_off, const float* __restrict__ b_off,
                            const float* __restrict__ w_dcn, const float* __restrict__ b_dcn,
                            float* __restrict__ ws) {
    int tid = blockIdx.x * blockDim.x + threadIdx.x;
    int nt = gridDim.x * blockDim.x;
    // w1 [64,128,5,5] -> w1r [c][25][64]
    for (int t = tid; t < 128 * 25 * 64; t += nt) {
        int o = t & 63; int rest = t >> 6; int tap = rest % 25; int c = rest / 25;
        ws[W1R_OFF + t] = w1[(o * 128 + c) * 25 + tap];
    }
    // w2 [64,64,3,3] -> w2r [c][9][64]
    for (int t = tid; t < 64 * 9 * 64; t += nt) {
        int o = t & 63; int rest = t >> 6; int tap = rest % 9; int c = rest / 9;
        ws[W2R_OFF + t] = w2[(o * 64 + c) * 9 + tap];
    }
    // w_off [27,64,3,3] -> woffr [c][9][27]
    for (int t = tid; t < 64 * 9 * 27; t += nt) {
        int o = t % 27; int rest = t / 27; int tap = rest % 9; int c = rest / 9;
        ws[WOFFR_OFF + t] = w_off[(o * 64 + c) * 9 + tap];
    }
    // w_dcn [64,64,9] -> wdcnr [ck][64]
    for (int t = tid; t < 576 * 64; t += nt) {
        int o = t & 63; int ck = t >> 6;
        ws[WDCNR_OFF + t] = w_dcn[o * 576 + ck];
    }
    if (tid < 64) {
        ws[B1_OFF + tid] = b1[tid];
        ws[B2_OFF + tid] = b2[tid];
        ws[BDCN_OFF + tid] = b_dcn[tid];
    }
    if (tid >= 64 && tid < 64 + 27) ws[BOFF_OFF + (tid - 64)] = b_off[tid - 64];
}

// ---------------- conv1: 5x5, Cin=128 (Fi||Fe), Cout=64, leaky ----------------
__global__ __launch_bounds__(256) void conv1_5x5(const float* __restrict__ Fi,
                                                 const float* __restrict__ Fe,
                                                 const float* __restrict__ wr,
                                                 const float* __restrict__ bias,
                                                 float* __restrict__ out) {
    const int w = threadIdx.x;                     // 0..127
    const int h = blockIdx.y * 2 + threadIdx.y;    // 0..127
    const int b = blockIdx.z;
    const int co0 = blockIdx.x * 32;
    float acc[32];
#pragma unroll
    for (int i = 0; i < 32; ++i) acc[i] = bias[co0 + i];

    for (int c = 0; c < 128; ++c) {
        const float* xp = ((c < 64) ? Fi : Fe) + (((size_t)(b * 64 + (c & 63))) << 14);
        const float* wc = wr + c * 25 * 64 + co0;
#pragma unroll
        for (int dy = 0; dy < 5; ++dy) {
            const int iy = h + dy - 2;
            if ((unsigned)iy < 128u) {
#pragma unroll
                for (int dx = 0; dx < 5; ++dx) {
                    const int ix = w + dx - 2;
                    float val = ((unsigned)ix < 128u) ? xp[(iy << 7) + ix] : 0.f;
                    const float* wt = wc + (dy * 5 + dx) * 64;
#pragma unroll
                    for (int i = 0; i < 32; ++i) acc[i] = fmaf(val, wt[i], acc[i]);
                }
            }
        }
    }
    const int p = (h << 7) + w;
#pragma unroll
    for (int i = 0; i < 32; ++i) {
        float v = acc[i];
        v = (v >= 0.f) ? v : 0.1f * v;
        out[(((size_t)(b * 64 + co0 + i)) << 14) + p] = v;
    }
}

// ---------------- generic 3x3 conv, Cin=64, f32 in/out ----------------
// OFFS: also write channels 0..17 to out0 (the offset output), no leaky.
template <int COUT, int CO_TILE, bool LEAKY, bool OFFS>
__global__ __launch_bounds__(256) void conv3(const float* __restrict__ x,
                                             const float* __restrict__ wr,
                                             const float* __restrict__ bias,
                                             float* __restrict__ out,
                                             float* __restrict__ out0) {
    const int w = threadIdx.x;
    const int h = blockIdx.y * 2 + threadIdx.y;
    const int b = blockIdx.z;
    const int co0 = blockIdx.x * CO_TILE;
    float acc[CO_TILE];
#pragma unroll
    for (int i = 0; i < CO_TILE; ++i) acc[i] = bias[co0 + i];

    for (int c = 0; c < 64; ++c) {
        const float* xp = x + (((size_t)(b * 64 + c)) << 14);
        const float* wc = wr + (c * 9) * COUT + co0;
#pragma unroll
        for (int dy = 0; dy < 3; ++dy) {
            const int iy = h + dy - 1;
            if ((unsigned)iy < 128u) {
#pragma unroll
                for (int dx = 0; dx < 3; ++dx) {
                    const int ix = w + dx - 1;
                    float val = ((unsigned)ix < 128u) ? xp[(iy << 7) + ix] : 0.f;
                    const float* wt = wc + (dy * 3 + dx) * COUT;
#pragma unroll
                    for (int i = 0; i < CO_TILE; ++i) acc[i] = fmaf(val, wt[i], acc[i]);
                }
            }
        }
    }
    const int p = (h << 7) + w;
#pragma unroll
    for (int i = 0; i < CO_TILE; ++i) {
        float v = acc[i];
        if (LEAKY) v = (v >= 0.f) ? v : 0.1f * v;
        out[((size_t)(b * COUT + co0 + i)) * HW + p] = v;
        if (OFFS) {
            const int ch = co0 + i;
            if (ch < 18) out0[((size_t)(b * 18 + ch)) * HW + p] = v;
        }
    }
}

// ---------------- copy Fi -> Ff[:, 0:64] (float4) ----------------
__global__ void copy_fi(const float* __restrict__ Fi, float* __restrict__ out1) {
    const int b = blockIdx.y;
    const int i = blockIdx.x * blockDim.x + threadIdx.x;   // 0..262143 float4 groups
    const int e = i << 2;                                   // element within batch
    const int c = e >> 14;
    const int p = e & 16383;
    const float4* src = reinterpret_cast<const float4*>(Fi);
    float4* dst = reinterpret_cast<float4*>(out1);
    size_t se = ((size_t)b << 20) + e;
    size_t de = (((size_t)(b * 128 + c)) << 14) + p;
    dst[de >> 2] = src[se >> 2];
}

// ---------------- DCNv2: sample Fe, modulate, einsum with w_dcn ----------------
__global__ __launch_bounds__(256) void dcn_kernel(const float* __restrict__ Fe,
                                                  const float* __restrict__ oo,
                                                  const float* __restrict__ wr,
                                                  const float* __restrict__ bias,
                                                  float* __restrict__ out1) {
    const int p = blockIdx.x * 256 + threadIdx.x;   // 0..16383
    const int b = blockIdx.y;
    const int h = p >> 7;
    const int w = p & 127;

    float acc[64];
#pragma unroll
    for (int o = 0; o < 64; ++o) acc[o] = bias[o];

    const float* oob = oo + (size_t)b * 27 * HW + p;
    const float* feb = Fe + ((size_t)b * 64 << 14);

    for (int k = 0; k < 9; ++k) {
        const int ky = k / 3, kx = k % 3;
        const float o1v = oob[(size_t)k << 14];
        const float o2v = oob[(size_t)(9 + k) << 14];
        const float ml  = oob[(size_t)(18 + k) << 14];
        const float m = 1.f / (1.f + expf(-ml));

        const float y = (float)(h - 1 + ky) + o1v;
        const float x = (float)(w - 1 + kx) + o2v;
        const float y0f = floorf(y), x0f = floorf(x);
        const float fy = y - y0f, fx = x - x0f;
        const int y0 = (int)y0f, x0 = (int)x0f;

        const bool vy0 = (unsigned)y0 < 128u;
        const bool vy1 = (unsigned)(y0 + 1) < 128u;
        const bool vx0 = (unsigned)x0 < 128u;
        const bool vx1 = (unsigned)(x0 + 1) < 128u;

        const int y0c = min(max(y0, 0), 127);
        const int y1c = min(max(y0 + 1, 0), 127);
        const int x0c = min(max(x0, 0), 127);
        const int x1c = min(max(x0 + 1, 0), 127);

        float w00 = (1.f - fy) * (1.f - fx) * m; w00 = (vy0 && vx0) ? w00 : 0.f;
        float w01 = (1.f - fy) * fx * m;         w01 = (vy0 && vx1) ? w01 : 0.f;
        float w10 = fy * (1.f - fx) * m;         w10 = (vy1 && vx0) ? w10 : 0.f;
        float w11 = fy * fx * m;                 w11 = (vy1 && vx1) ? w11 : 0.f;

        const int i00 = (y0c << 7) + x0c;
        const int i01 = (y0c << 7) + x1c;
        const int i10 = (y1c << 7) + x0c;
        const int i11 = (y1c << 7) + x1c;

        for (int c = 0; c < 64; ++c) {
            const float* f = feb + ((size_t)c << 14);
            const float v00 = f[i00];
            const float v01 = f[i01];
            const float v10 = f[i10];
            const float v11 = f[i11];
            const float s = w00 * v00 + w01 * v01 + w10 * v10 + w11 * v11;
            const float* wt = wr + (c * 9 + k) * 64;
#pragma unroll
            for (int o = 0; o < 64; ++o) acc[o] = fmaf(s, wt[o], acc[o]);
        }
    }

#pragma unroll
    for (int o = 0; o < 64; ++o) {
        out1[(((size_t)(b * 128 + 64 + o)) << 14) + p] = acc[o];
    }
}

extern "C" void kernel_launch(void* const* d_in, const int* in_sizes, int n_in,
                              void* d_out, int out_size, void* d_ws, size_t ws_size,
                              hipStream_t stream) {
    const float* Fi    = (const float*)d_in[0];
    const float* Fe    = (const float*)d_in[1];
    const float* w1    = (const float*)d_in[2];
    const float* b1    = (const float*)d_in[3];
    const float* w2    = (const float*)d_in[4];
    const float* b2    = (const float*)d_in[5];
    const float* w_off = (const float*)d_in[6];
    const float* b_off = (const float*)d_in[7];
    const float* w_dcn = (const float*)d_in[8];
    const float* b_dcn = (const float*)d_in[9];

    float* ws = (float*)d_ws;
    float* w1r   = ws + W1R_OFF;
    float* w2r   = ws + W2R_OFF;
    float* woffr = ws + WOFFR_OFF;
    float* wdcnr = ws + WDCNR_OFF;
    float* b1f   = ws + B1_OFF;
    float* b2f   = ws + B2_OFF;
    float* bofff = ws + BOFF_OFF;
    float* bdcnf = ws + BDCN_OFF;
    float* feat1 = ws + FEAT1_OFF;
    float* feat2 = ws + FEAT2_OFF;
    float* oo    = ws + OO_OFF;

    float* out0 = (float*)d_out;                   // offset_out [8,18,128,128]
    float* out1 = out0 + (size_t)Bn * 18 * HW;     // Ff [8,128,128,128]

    prep_kernel<<<256, 256, 0, stream>>>(w1, b1, w2, b2, w_off, b_off, w_dcn, b_dcn, ws);

    conv1_5x5<<<dim3(2, 64, 8), dim3(128, 2), 0, stream>>>(Fi, Fe, w1r, b1f, feat1);

    conv3<64, 32, true, false><<<dim3(2, 64, 8), dim3(128, 2), 0, stream>>>(feat1, w2r, b2f, feat2, nullptr);

    conv3<27, 27, false, true><<<dim3(1, 64, 8), dim3(128, 2), 0, stream>>>(feat2, woffr, bofff, oo, out0);

    copy_fi<<<dim3(1024, 8), 256, 0, stream>>>(Fi, out1);

    dcn_kernel<<<dim3(64, 8), 256, 0, stream>>>(Fe, oo, wdcnr, bdcnf, out1);
}

// Round 3
// 550.245 us; speedup vs baseline: 3.3854x; 3.3854x over previous
//
#include <hip/hip_runtime.h>
#include <hip/hip_bf16.h>

typedef __bf16 bf16_t;
typedef __attribute__((ext_vector_type(8))) __bf16 bf16x8;
typedef __attribute__((ext_vector_type(4))) float f32x4;

#define Bn 8
#define Hh 128
#define Ww 128
#define HW 16384

// ---- ws byte-offset layout ----
#define WP1_B   ((size_t)0)          // 25*4*4*64*8 bf16 = 409600 B
#define WP2_B   ((size_t)409600)     // 9*2*4*64*8 bf16  = 73728 B
#define WPO_B   ((size_t)483328)     // 9*2*4*32*8 bf16  = 36864 B
#define WDCN_B  ((size_t)520192)     // 576*64 f32       = 147456 B
#define BIAS_B  ((size_t)667648)     // 224 f32 (b1[64] b2[64] boff[32] bdcn[64])
#define XT_B    ((size_t)668672)     // 8*16384*128 bf16 = 33554432 B   (feat2 aliases this after conv1 input is dead)
#define F1_B    (XT_B + 33554432)    // feat1: 8*16384*64 bf16 = 16777216 B (OO f32 aliases this after conv2)
// total = 51,000,320 B

// ---------------- prep: swizzle weights into MFMA B-fragment order ----------------
// Wp[t][ck][g][n][j] = W[o=n][cin=ck*32+g*8+j][tap t]   (bf16)
__global__ void prep_kernel(const float* __restrict__ w1, const float* __restrict__ w2,
                            const float* __restrict__ woff, const float* __restrict__ wdcn,
                            const float* __restrict__ b1, const float* __restrict__ b2,
                            const float* __restrict__ boff, const float* __restrict__ bdcn,
                            char* __restrict__ wsb) {
    bf16_t* wp1 = (bf16_t*)(wsb + WP1_B);
    bf16_t* wp2 = (bf16_t*)(wsb + WP2_B);
    bf16_t* wpo = (bf16_t*)(wsb + WPO_B);
    float*  wd  = (float*)(wsb + WDCN_B);
    float*  bias= (float*)(wsb + BIAS_B);
    int tid = blockIdx.x * blockDim.x + threadIdx.x;
    int nt  = gridDim.x * blockDim.x;
    for (int i = tid; i < 25*4*4*64*8; i += nt) {
        int j = i & 7, q = i >> 3;
        int n = q % 64; q /= 64;
        int g = q & 3;  q >>= 2;
        int ck = q & 3; int t = q >> 2;
        int cin = ck*32 + g*8 + j;
        wp1[i] = (bf16_t)w1[(n*128 + cin)*25 + t];
    }
    for (int i = tid; i < 9*2*4*64*8; i += nt) {
        int j = i & 7, q = i >> 3;
        int n = q % 64; q /= 64;
        int g = q & 3;  q >>= 2;
        int ck = q & 1; int t = q >> 1;
        int cin = ck*32 + g*8 + j;
        wp2[i] = (bf16_t)w2[(n*64 + cin)*9 + t];
    }
    for (int i = tid; i < 9*2*4*32*8; i += nt) {
        int j = i & 7, q = i >> 3;
        int n = q & 31; q >>= 5;
        int g = q & 3;  q >>= 2;
        int ck = q & 1; int t = q >> 1;
        int cin = ck*32 + g*8 + j;
        wpo[i] = (n < 27) ? (bf16_t)woff[(n*64 + cin)*9 + t] : (bf16_t)0.f;
    }
    for (int i = tid; i < 576*64; i += nt) {
        int o = i & 63, ck = i >> 6;
        wd[i] = wdcn[o*576 + ck];
    }
    if (tid < 64) { bias[tid] = b1[tid]; bias[64+tid] = b2[tid]; bias[160+tid] = bdcn[tid]; }
    if (tid >= 64 && tid < 96) { int n = tid - 64; bias[128+n] = (n < 27) ? boff[n] : 0.f; }
}

// ---------------- NCHW f32 (Fi||Fe) -> NHWC bf16 Xt[b][p][128] ----------------
__global__ __launch_bounds__(256) void nhwc_kernel(const float* __restrict__ Fi,
                                                   const float* __restrict__ Fe,
                                                   bf16_t* __restrict__ Xt) {
    __shared__ bf16_t tile[64][136];
    const int b  = blockIdx.y;
    const int p0 = blockIdx.x * 64;
    const int px = threadIdx.x & 63;
    const int csub = threadIdx.x >> 6;     // 0..3
    for (int ci = 0; ci < 32; ++ci) {
        int c = csub * 32 + ci;            // 0..127
        const float* src = (c < 64) ? (Fi + (((size_t)(b*64 + c)) << 14))
                                    : (Fe + (((size_t)(b*64 + (c-64))) << 14));
        tile[px][c] = (bf16_t)src[p0 + px];
    }
    __syncthreads();
    const int px2 = threadIdx.x >> 2;
    const int cc  = (threadIdx.x & 3) * 32;
    bf16x8* dst = (bf16x8*)(Xt + ((size_t)(b*HW) + p0 + px2) * 128 + cc);
    const bf16x8* srcl = (const bf16x8*)(&tile[px2][cc]);
    dst[0] = srcl[0]; dst[1] = srcl[1]; dst[2] = srcl[2]; dst[3] = srcl[3];
}

// ---------------- implicit-GEMM conv via mfma_f32_16x16x32_bf16 ----------------
// Block: 256 thr = 4 waves, WM x WN wave grid. Wave tile = 32 px (one row) x 32 co.
// Block tile: M = WM rows x 32 cols, N = WN*32 (= COUTP).
// LDS stages halo tile [HR rows][HC cols][32 ch] per K-chunk, ch-stride padded to 40.
template <int CIN_, int KS, int WM, int WN, bool LEAKY, int COUTP, bool OUTF32>
__global__ __launch_bounds__(256) void conv_mfma(const bf16_t* __restrict__ Xt,
                                                 const bf16_t* __restrict__ Wp,
                                                 const float* __restrict__ bias,
                                                 bf16_t* __restrict__ outb,
                                                 float* __restrict__ outf) {
    constexpr int PAD = KS / 2;
    constexpr int HR  = WM + KS - 1;
    constexpr int HC  = 32 + KS - 1;
    constexpr int NC  = CIN_ / 32;     // K-chunks of 32
    __shared__ bf16_t stg[HR * HC * 40];

    const int tid  = threadIdx.x;
    const int lane = tid & 63;
    const int wid  = tid >> 6;
    const int wm   = wid / WN;
    const int wn   = wid % WN;
    const int b    = blockIdx.z;
    const int h0   = blockIdx.y * WM;
    const int w0   = blockIdx.x * 32;
    const int l15  = lane & 15;
    const int l4   = lane >> 4;        // 0..3

    f32x4 acc[2][2];
#pragma unroll
    for (int i = 0; i < 2; ++i)
#pragma unroll
        for (int j = 0; j < 2; ++j)
#pragma unroll
            for (int r = 0; r < 4; ++r) acc[i][j][r] = 0.f;

    // staging assignment: one (row,col) site per thread
    const int site = tid;
    const int srow = site / HC, scol = site % HC;
    const int gh = h0 - PAD + srow, gw = w0 - PAD + scol;
    const bool active = site < HR * HC;
    const bool inb = active && ((unsigned)gh < 128u) && ((unsigned)gw < 128u);
    const bf16_t Z0 = (bf16_t)0.f;
    const bf16x8 zv = {Z0, Z0, Z0, Z0, Z0, Z0, Z0, Z0};

    const bf16x8* wpt = (const bf16x8*)Wp;

    for (int ck = 0; ck < NC; ++ck) {
        if (active) {
            bf16x8 v0 = zv, v1 = zv, v2 = zv, v3 = zv;
            if (inb) {
                const bf16x8* gp = (const bf16x8*)(Xt + (((size_t)(b*HW) + (gh << 7) + gw)) * CIN_ + ck * 32);
                v0 = gp[0]; v1 = gp[1]; v2 = gp[2]; v3 = gp[3];
            }
            bf16x8* ldst = (bf16x8*)(&stg[site * 40]);
            ldst[0] = v0; ldst[1] = v1; ldst[2] = v2; ldst[3] = v3;
        }
        __syncthreads();
        int t = 0;
#pragma unroll
        for (int dy = 0; dy < KS; ++dy) {
#pragma unroll
            for (int dx = 0; dx < KS; ++dx, ++t) {
                bf16x8 a0 = *(const bf16x8*)(&stg[((wm + dy) * HC + (l15 + dx)) * 40 + l4 * 8]);
                bf16x8 a1 = *(const bf16x8*)(&stg[((wm + dy) * HC + (16 + l15 + dx)) * 40 + l4 * 8]);
                const bf16x8* wb = wpt + ((size_t)((t * NC + ck) * 4 + l4)) * COUTP + wn * 32 + l15;
                bf16x8 b0 = wb[0];
                bf16x8 b1 = wb[16];
                acc[0][0] = __builtin_amdgcn_mfma_f32_16x16x32_bf16(a0, b0, acc[0][0], 0, 0, 0);
                acc[0][1] = __builtin_amdgcn_mfma_f32_16x16x32_bf16(a0, b1, acc[0][1], 0, 0, 0);
                acc[1][0] = __builtin_amdgcn_mfma_f32_16x16x32_bf16(a1, b0, acc[1][0], 0, 0, 0);
                acc[1][1] = __builtin_amdgcn_mfma_f32_16x16x32_bf16(a1, b1, acc[1][1], 0, 0, 0);
            }
        }
        __syncthreads();
    }

    // epilogue: C/D layout (16x16): col n = lane&15, row m = (lane>>4)*4 + reg
    const int hrow = h0 + wm;
#pragma unroll
    for (int mh = 0; mh < 2; ++mh) {
#pragma unroll
        for (int nh = 0; nh < 2; ++nh) {
            const int n = wn * 32 + nh * 16 + l15;
            const float bs = bias[n];
#pragma unroll
            for (int r = 0; r < 4; ++r) {
                const int px = w0 + mh * 16 + l4 * 4 + r;
                float v = acc[mh][nh][r] + bs;
                if (LEAKY) v = (v >= 0.f) ? v : 0.1f * v;
                const size_t pbase = (size_t)(b * HW) + (hrow << 7) + px;
                if (OUTF32) outf[pbase * COUTP + n] = v;
                else        outb[pbase * COUTP + n] = (bf16_t)v;
            }
        }
    }
}

// ---------------- oo NHWC f32 -> out0 NCHW f32 (ch 0..17) ----------------
__global__ __launch_bounds__(256) void oo_transpose(const float* __restrict__ OO,
                                                    float* __restrict__ out0) {
    const int i = blockIdx.x * 256 + threadIdx.x;   // b*HW + p
    const int b = i >> 14, p = i & 16383;
    const float* src = OO + (size_t)i * 32;
#pragma unroll
    for (int ch = 0; ch < 18; ++ch)
        out0[(((size_t)(b * 18 + ch)) << 14) + p] = src[ch];
}

// ---------------- copy Fi -> Ff[:, 0:64] (float4) ----------------
__global__ void copy_fi(const float* __restrict__ Fi, float* __restrict__ out1) {
    const int b = blockIdx.y;
    const int i = blockIdx.x * blockDim.x + threadIdx.x;
    const int e = i << 2;
    const int c = e >> 14;
    const int p = e & 16383;
    const float4* src = reinterpret_cast<const float4*>(Fi);
    float4* dst = reinterpret_cast<float4*>(out1);
    size_t se = ((size_t)b << 20) + e;
    size_t de = (((size_t)(b * 128 + c)) << 14) + p;
    dst[de >> 2] = src[se >> 2];
}

// ---------------- DCNv2: sample Fe (f32 NCHW), oo NHWC, einsum ----------------
__global__ __launch_bounds__(256) void dcn_kernel(const float* __restrict__ Fe,
                                                  const float* __restrict__ oo,
                                                  const float* __restrict__ wr,
                                                  const float* __restrict__ bias,
                                                  float* __restrict__ out1) {
    const int p = blockIdx.x * 256 + threadIdx.x;
    const int b = blockIdx.y;
    const int h = p >> 7;
    const int w = p & 127;

    float acc[64];
#pragma unroll
    for (int o = 0; o < 64; ++o) acc[o] = bias[o];

    const float* oob = oo + ((size_t)(b * HW) + p) * 32;
    const float* feb = Fe + ((size_t)b * 64 << 14);

    for (int k = 0; k < 9; ++k) {
        const int ky = k / 3, kx = k % 3;
        const float o1v = oob[k];
        const float o2v = oob[9 + k];
        const float ml  = oob[18 + k];
        const float m = 1.f / (1.f + expf(-ml));

        const float y = (float)(h - 1 + ky) + o1v;
        const float x = (float)(w - 1 + kx) + o2v;
        const float y0f = floorf(y), x0f = floorf(x);
        const float fy = y - y0f, fx = x - x0f;
        const int y0 = (int)y0f, x0 = (int)x0f;

        const bool vy0 = (unsigned)y0 < 128u;
        const bool vy1 = (unsigned)(y0 + 1) < 128u;
        const bool vx0 = (unsigned)x0 < 128u;
        const bool vx1 = (unsigned)(x0 + 1) < 128u;

        const int y0c = min(max(y0, 0), 127);
        const int y1c = min(max(y0 + 1, 0), 127);
        const int x0c = min(max(x0, 0), 127);
        const int x1c = min(max(x0 + 1, 0), 127);

        float w00 = (1.f - fy) * (1.f - fx) * m; w00 = (vy0 && vx0) ? w00 : 0.f;
        float w01 = (1.f - fy) * fx * m;         w01 = (vy0 && vx1) ? w01 : 0.f;
        float w10 = fy * (1.f - fx) * m;         w10 = (vy1 && vx0) ? w10 : 0.f;
        float w11 = fy * fx * m;                 w11 = (vy1 && vx1) ? w11 : 0.f;

        const int i00 = (y0c << 7) + x0c;
        const int i01 = (y0c << 7) + x1c;
        const int i10 = (y1c << 7) + x0c;
        const int i11 = (y1c << 7) + x1c;

        for (int c = 0; c < 64; ++c) {
            const float* f = feb + ((size_t)c << 14);
            const float s = w00 * f[i00] + w01 * f[i01] + w10 * f[i10] + w11 * f[i11];
            const float* wt = wr + (c * 9 + k) * 64;
#pragma unroll
            for (int o = 0; o < 64; ++o) acc[o] = fmaf(s, wt[o], acc[o]);
        }
    }

#pragma unroll
    for (int o = 0; o < 64; ++o) {
        out1[(((size_t)(b * 128 + 64 + o)) << 14) + p] = acc[o];
    }
}

extern "C" void kernel_launch(void* const* d_in, const int* in_sizes, int n_in,
                              void* d_out, int out_size, void* d_ws, size_t ws_size,
                              hipStream_t stream) {
    const float* Fi    = (const float*)d_in[0];
    const float* Fe    = (const float*)d_in[1];
    const float* w1    = (const float*)d_in[2];
    const float* b1    = (const float*)d_in[3];
    const float* w2    = (const float*)d_in[4];
    const float* b2    = (const float*)d_in[5];
    const float* w_off = (const float*)d_in[6];
    const float* b_off = (const float*)d_in[7];
    const float* w_dcn = (const float*)d_in[8];
    const float* b_dcn = (const float*)d_in[9];

    char* wsb = (char*)d_ws;
    bf16_t* wp1   = (bf16_t*)(wsb + WP1_B);
    bf16_t* wp2   = (bf16_t*)(wsb + WP2_B);
    bf16_t* wpo   = (bf16_t*)(wsb + WPO_B);
    float*  wdcnr = (float*)(wsb + WDCN_B);
    float*  bias  = (float*)(wsb + BIAS_B);
    bf16_t* Xt    = (bf16_t*)(wsb + XT_B);
    bf16_t* feat1 = (bf16_t*)(wsb + F1_B);
    bf16_t* feat2 = (bf16_t*)(wsb + XT_B);   // alias: conv1 input dead after conv1
    float*  OO    = (float*)(wsb + F1_B);    // alias: feat1 dead after conv2

    float* out0 = (float*)d_out;                   // offset_out [8,18,128,128]
    float* out1 = out0 + (size_t)Bn * 18 * HW;     // Ff [8,128,128,128]

    prep_kernel<<<256, 256, 0, stream>>>(w1, w2, w_off, w_dcn, b1, b2, b_off, b_dcn, wsb);

    nhwc_kernel<<<dim3(256, 8), 256, 0, stream>>>(Fi, Fe, Xt);

    conv_mfma<128, 5, 2, 2, true, 64, false>
        <<<dim3(4, 64, 8), 256, 0, stream>>>(Xt, wp1, bias, feat1, nullptr);

    conv_mfma<64, 3, 2, 2, true, 64, false>
        <<<dim3(4, 64, 8), 256, 0, stream>>>(feat1, wp2, bias + 64, feat2, nullptr);

    conv_mfma<64, 3, 4, 1, false, 32, true>
        <<<dim3(4, 32, 8), 256, 0, stream>>>(feat2, wpo, bias + 128, nullptr, OO);

    oo_transpose<<<512, 256, 0, stream>>>(OO, out0);

    copy_fi<<<dim3(1024, 8), 256, 0, stream>>>(Fi, out1);

    dcn_kernel<<<dim3(64, 8), 256, 0, stream>>>(Fe, OO, wdcnr, bias + 160, out1);
}